// Round 1
// baseline (502.373 us; speedup 1.0000x reference)
//
#include <hip/hip_runtime.h>
#include <hip/hip_bf16.h>

#define B_ 4
#define H_ 16
#define S_ 2048
#define DM_ 1024

typedef float f32x4 __attribute__((ext_vector_type(4)));
typedef short bf16x8 __attribute__((ext_vector_type(8)));
typedef unsigned short u16;
typedef u16 u16x4 __attribute__((ext_vector_type(4)));
typedef u16 u16x8 __attribute__((ext_vector_type(8)));

__device__ __forceinline__ u16 f2bf(float f) {
  union { float f; unsigned u; } v; v.f = f;
  unsigned r = v.u + 0x7fffu + ((v.u >> 16) & 1u);
  return (u16)(r >> 16);
}

// ---------------- W transpose + bf16 convert (+ fold 1/8 into WQ) ----------------
__global__ __launch_bounds__(256) void ktrans(const float* __restrict__ WQ,
                                              const float* __restrict__ WK,
                                              const float* __restrict__ WV,
                                              u16* __restrict__ Wt) {
  int z = blockIdx.z;
  const float* W = (z == 0) ? WQ : (z == 1) ? WK : WV;
  u16* o = Wt + (size_t)z * DM_ * DM_;
  float scale = (z == 0) ? 0.125f : 1.0f;
  __shared__ float tl[32][33];
  int tx = threadIdx.x & 31, ty = threadIdx.x >> 5;
  int ko = blockIdx.x * 32, no = blockIdx.y * 32;
#pragma unroll
  for (int i = 0; i < 32; i += 8)
    tl[ty + i][tx] = W[(size_t)(ko + ty + i) * DM_ + no + tx];
  __syncthreads();
#pragma unroll
  for (int i = 0; i < 32; i += 8)
    o[(size_t)(no + ty + i) * DM_ + ko + tx] = f2bf(tl[tx][ty + i] * scale);
}

// ---------------- projection GEMM: [8192x1024]f32 @ Wt^T -> bf16 ws ----------------
// z=0: Q (scaled via Wt), z=1: K  -> layout [b,h,s,d]
// z=2: V -> layout [b,h,d,s] (transposed for PV B-operand)
__global__ __launch_bounds__(256, 2) void kproj(
    const float* __restrict__ A0, const float* __restrict__ A1, const float* __restrict__ A2,
    const u16* __restrict__ Wt, u16* __restrict__ Qw, u16* __restrict__ Kw, u16* __restrict__ Vt) {
  int z = blockIdx.z;
  const float* A = (z == 0) ? A0 : (z == 1) ? A1 : A2;
  const u16* Wz = Wt + (size_t)z * DM_ * DM_;
  __shared__ __align__(16) u16 lds[2 * 128 * 64];  // A tile @0, B tile @8192 (both [row][64] k-major, swizzled)
  int t = threadIdx.x;
  int lane = t & 63, w = t >> 6;
  int wm = (w >> 1) * 64, wn = (w & 1) * 64;
  int m0 = blockIdx.y * 128, n0 = blockIdx.x * 128;
  f32x4 acc[4][4];
#pragma unroll
  for (int i = 0; i < 4; ++i)
#pragma unroll
    for (int j = 0; j < 4; ++j) acc[i][j] = (f32x4){0.f, 0.f, 0.f, 0.f};

  int ka = (t & 15) * 4, ma = t >> 4;  // A staging coords
  int kb = (t & 7) * 8, nb = t >> 3;   // B staging coords

  for (int k0 = 0; k0 < DM_; k0 += 64) {
    __syncthreads();
#pragma unroll
    for (int p = 0; p < 8; ++p) {  // stage A: [128 m][64 k] f32->bf16
      int m = ma + p * 16;
      f32x4 v = *(const f32x4*)(A + (size_t)(m0 + m) * DM_ + k0 + ka);
      u16x4 hv = {f2bf(v.x), f2bf(v.y), f2bf(v.z), f2bf(v.w)};
      *(u16x4*)(&lds[m * 64 + (ka ^ ((m & 7) << 3))]) = hv;
    }
#pragma unroll
    for (int p = 0; p < 4; ++p) {  // stage B: Wt rows [128 n][64 k] bf16
      int n = nb + p * 32;
      u16x8 v = *(const u16x8*)(Wz + (size_t)(n0 + n) * DM_ + k0 + kb);
      *(u16x8*)(&lds[8192 + n * 64 + (kb ^ ((n & 7) << 3))]) = v;
    }
    __syncthreads();
#pragma unroll
    for (int kk = 0; kk < 64; kk += 32) {
      int ko8 = kk + ((lane >> 4) << 3);
      bf16x8 af[4], bfr[4];
#pragma unroll
      for (int mi = 0; mi < 4; ++mi) {
        int r = wm + mi * 16 + (lane & 15);
        af[mi] = *(const bf16x8*)(&lds[r * 64 + (ko8 ^ ((r & 7) << 3))]);
      }
#pragma unroll
      for (int ni = 0; ni < 4; ++ni) {
        int r = wn + ni * 16 + (lane & 15);
        bfr[ni] = *(const bf16x8*)(&lds[8192 + r * 64 + (ko8 ^ ((r & 7) << 3))]);
      }
#pragma unroll
      for (int mi = 0; mi < 4; ++mi)
#pragma unroll
        for (int ni = 0; ni < 4; ++ni)
          acc[mi][ni] = __builtin_amdgcn_mfma_f32_16x16x32_bf16(af[mi], bfr[ni], acc[mi][ni], 0, 0, 0);
    }
  }
  // epilogue: C row=(lane>>4)*4+j, col=lane&15 (HW-verified layout)
  int bb = m0 >> 11;
  if (z < 2) {
    u16* o = (z == 0) ? Qw : Kw;
#pragma unroll
    for (int mi = 0; mi < 4; ++mi) {
      int m4 = m0 + wm + mi * 16 + ((lane >> 4) << 2);
      int s4 = m4 & 2047;
#pragma unroll
      for (int ni = 0; ni < 4; ++ni) {
        int n = n0 + wn + ni * 16 + (lane & 15);
        int hh = n >> 6, d = n & 63;
        u16* op = o + (((size_t)(bb * 16 + hh) * 2048 + s4) * 64 + d);
#pragma unroll
        for (int j = 0; j < 4; ++j) op[(size_t)j * 64] = f2bf(acc[mi][ni][j]);
      }
    }
  } else {
#pragma unroll
    for (int mi = 0; mi < 4; ++mi) {
      int m4 = m0 + wm + mi * 16 + ((lane >> 4) << 2);
      int s4 = m4 & 2047;
#pragma unroll
      for (int ni = 0; ni < 4; ++ni) {
        int n = n0 + wn + ni * 16 + (lane & 15);
        int hh = n >> 6, d = n & 63;
        u16x4 pv = {f2bf(acc[mi][ni][0]), f2bf(acc[mi][ni][1]),
                    f2bf(acc[mi][ni][2]), f2bf(acc[mi][ni][3])};
        *(u16x4*)(&Vt[((size_t)(bb * 16 + hh) * 64 + d) * 2048 + s4]) = pv;
      }
    }
  }
}

// ---------------- flash attention: QBLK=128 (4 waves x 32q), KVBLK=64 ----------------
__global__ __launch_bounds__(256, 2) void kattn(
    const u16* __restrict__ Qw, const u16* __restrict__ Kw, const u16* __restrict__ Vt,
    const int* __restrict__ Qlen, const int* __restrict__ Vlen, float* __restrict__ out) {
  int bh = blockIdx.y;
  int b = bh >> 4, h = bh & 15;
  int q0 = blockIdx.x * 128;
  int t = threadIdx.x, lane = t & 63, w = t >> 6;
  // [0..8191]: Q tile, later K tile(0..4095) + V^T tile(4096..8191); [8192..16383]: P (wave-private 2048 each)
  __shared__ __align__(16) u16 smem[16384];
  const int qlen = Qlen[b], vlen = Vlen[b];

  {  // stage Q [128][64]
    int d8 = (t & 7) * 8, sA = t >> 3;
#pragma unroll
    for (int p = 0; p < 4; ++p) {
      int s = sA + p * 32;
      u16x8 v = *(const u16x8*)(Qw + ((size_t)bh * 2048 + q0 + s) * 64 + d8);
      *(u16x8*)(&smem[s * 64 + (d8 ^ ((s & 7) << 3))]) = v;
    }
  }
  __syncthreads();
  bf16x8 qf[2][2];
#pragma unroll
  for (int qi = 0; qi < 2; ++qi) {
    int r = w * 32 + qi * 16 + (lane & 15);
#pragma unroll
    for (int kf = 0; kf < 2; ++kf) {
      int off = kf * 32 + ((lane >> 4) << 3);
      qf[qi][kf] = *(const bf16x8*)(&smem[r * 64 + (off ^ ((r & 7) << 3))]);
    }
  }
  __syncthreads();

  float M[2][4], L[2][4];
  f32x4 o[2][4];
#pragma unroll
  for (int qi = 0; qi < 2; ++qi)
#pragma unroll
    for (int j = 0; j < 4; ++j) { M[qi][j] = -1e30f; L[qi][j] = 0.f; }
#pragma unroll
  for (int qi = 0; qi < 2; ++qi)
#pragma unroll
    for (int df = 0; df < 4; ++df) o[qi][df] = (f32x4){0.f, 0.f, 0.f, 0.f};

  int d8 = (t & 7) * 8, rA = t >> 3;
  const int pbase = 8192 + w * 2048;

  for (int kt = 0; kt < 32; ++kt) {
    int kb0 = kt * 64;
#pragma unroll
    for (int p = 0; p < 2; ++p) {  // stage K [64 s][64 d]
      int s = rA + p * 32;
      u16x8 v = *(const u16x8*)(Kw + ((size_t)bh * 2048 + kb0 + s) * 64 + d8);
      *(u16x8*)(&smem[s * 64 + (d8 ^ ((s & 7) << 3))]) = v;
    }
#pragma unroll
    for (int p = 0; p < 2; ++p) {  // stage V^T [64 d][64 s]
      int d = rA + p * 32;
      u16x8 v = *(const u16x8*)(Vt + ((size_t)bh * 64 + d) * 2048 + kb0 + d8);
      *(u16x8*)(&smem[4096 + d * 64 + (d8 ^ ((d & 7) << 3))]) = v;
    }
    __syncthreads();

    f32x4 sa[2][4];
#pragma unroll
    for (int qi = 0; qi < 2; ++qi)
#pragma unroll
      for (int c = 0; c < 4; ++c) sa[qi][c] = (f32x4){0.f, 0.f, 0.f, 0.f};
#pragma unroll
    for (int kf = 0; kf < 2; ++kf) {  // S = Q K^T (scale pre-folded into WQ)
      int off = kf * 32 + ((lane >> 4) << 3);
      bf16x8 kfr[4];
#pragma unroll
      for (int c = 0; c < 4; ++c) {
        int r = c * 16 + (lane & 15);
        kfr[c] = *(const bf16x8*)(&smem[r * 64 + (off ^ ((r & 7) << 3))]);
      }
#pragma unroll
      for (int qi = 0; qi < 2; ++qi)
#pragma unroll
        for (int c = 0; c < 4; ++c)
          sa[qi][c] = __builtin_amdgcn_mfma_f32_16x16x32_bf16(qf[qi][kf], kfr[c], sa[qi][c], 0, 0, 0);
    }
    // V_len key mask (single column -> -1e12, exp underflows to exact 0)
#pragma unroll
    for (int c = 0; c < 4; ++c) {
      if (kb0 + c * 16 + (lane & 15) == vlen) {
#pragma unroll
        for (int qi = 0; qi < 2; ++qi)
#pragma unroll
          for (int j = 0; j < 4; ++j) sa[qi][c][j] = -1e12f;
      }
    }
    // online softmax (rows live in 16-lane groups) + P -> wave-private LDS
#pragma unroll
    for (int qi = 0; qi < 2; ++qi) {
#pragma unroll
      for (int j = 0; j < 4; ++j) {
        float mx = fmaxf(fmaxf(sa[qi][0][j], sa[qi][1][j]), fmaxf(sa[qi][2][j], sa[qi][3][j]));
#pragma unroll
        for (int dd = 1; dd < 16; dd <<= 1) mx = fmaxf(mx, __shfl_xor(mx, dd, 64));
        float Mn = fmaxf(M[qi][j], mx);
        float al = __expf(M[qi][j] - Mn);
        M[qi][j] = Mn;
        float rs = 0.f;
#pragma unroll
        for (int c = 0; c < 4; ++c) {
          float p = __expf(sa[qi][c][j] - Mn);
          sa[qi][c][j] = p;
          rs += p;
        }
#pragma unroll
        for (int dd = 1; dd < 16; dd <<= 1) rs += __shfl_xor(rs, dd, 64);
        L[qi][j] = L[qi][j] * al + rs;
#pragma unroll
        for (int df = 0; df < 4; ++df) o[qi][df][j] *= al;
        int pr = qi * 16 + ((lane >> 4) << 2) + j;
#pragma unroll
        for (int c = 0; c < 4; ++c)
          smem[pbase + pr * 64 + ((c * 16 + (lane & 15)) ^ ((pr & 7) << 3))] = f2bf(sa[qi][c][j]);
      }
    }
    // O += P V
#pragma unroll
    for (int kf = 0; kf < 2; ++kf) {
      int off = kf * 32 + ((lane >> 4) << 3);
      bf16x8 pf[2];
#pragma unroll
      for (int qi = 0; qi < 2; ++qi) {
        int r = qi * 16 + (lane & 15);
        pf[qi] = *(const bf16x8*)(&smem[pbase + r * 64 + (off ^ ((r & 7) << 3))]);
      }
#pragma unroll
      for (int df = 0; df < 4; ++df) {
        int r = df * 16 + (lane & 15);
        bf16x8 vf = *(const bf16x8*)(&smem[4096 + r * 64 + (off ^ ((r & 7) << 3))]);
#pragma unroll
        for (int qi = 0; qi < 2; ++qi)
          o[qi][df] = __builtin_amdgcn_mfma_f32_16x16x32_bf16(pf[qi], vf, o[qi][df], 0, 0, 0);
      }
    }
    __syncthreads();
  }
  // epilogue: /L, zero q==Q_len row, f32 out [b, s, h*64+d]
#pragma unroll
  for (int qi = 0; qi < 2; ++qi) {
#pragma unroll
    for (int j = 0; j < 4; ++j) {
      int q = q0 + w * 32 + qi * 16 + ((lane >> 4) << 2) + j;
      float inv = 1.f / L[qi][j];
      bool zero = (q == qlen);
#pragma unroll
      for (int df = 0; df < 4; ++df) {
        float val = zero ? 0.f : o[qi][df][j] * inv;
        out[((size_t)b * 2048 + q) * 1024 + h * 64 + df * 16 + (lane & 15)] = val;
      }
    }
  }
}

extern "C" void kernel_launch(void* const* d_in, const int* in_sizes, int n_in,
                              void* d_out, int out_size, void* d_ws, size_t ws_size,
                              hipStream_t stream) {
  (void)in_sizes; (void)n_in; (void)out_size; (void)ws_size;
  const float* Qs = (const float*)d_in[0];
  const float* Ks = (const float*)d_in[1];
  const float* Vs = (const float*)d_in[2];
  const int* Ql = (const int*)d_in[3];
  const int* Vl = (const int*)d_in[4];
  const float* WQ = (const float*)d_in[5];
  const float* WK = (const float*)d_in[6];
  const float* WV = (const float*)d_in[7];
  float* out = (float*)d_out;

  u16* Wt = (u16*)d_ws;                              // 3 * 1M bf16 = 6 MB
  u16* Qw = Wt + (size_t)3 * 1024 * 1024;            // 8M bf16 = 16 MB
  u16* Kw = Qw + (size_t)8 * 1024 * 1024;
  u16* Vtw = Kw + (size_t)8 * 1024 * 1024;           // total ~54 MB

  ktrans<<<dim3(32, 32, 3), 256, 0, stream>>>(WQ, WK, WV, Wt);
  kproj<<<dim3(8, 64, 3), 256, 0, stream>>>(Qs, Ks, Vs, Wt, Qw, Kw, Vtw);
  kattn<<<dim3(16, 64), 256, 0, stream>>>(Qw, Kw, Vtw, Ql, Vl, out);
}

// Round 2
// 328.343 us; speedup vs baseline: 1.5300x; 1.5300x over previous
//
#include <hip/hip_runtime.h>
#include <hip/hip_bf16.h>

typedef float f32x4 __attribute__((ext_vector_type(4)));
typedef float f32x16 __attribute__((ext_vector_type(16)));
typedef short bf16x8 __attribute__((ext_vector_type(8)));
typedef unsigned short u16;
typedef u16 u16x4 __attribute__((ext_vector_type(4)));
typedef u16 u16x8 __attribute__((ext_vector_type(8)));
typedef unsigned u32;
typedef unsigned u32x2 __attribute__((ext_vector_type(2)));

#define GLDS(gp, lp) __builtin_amdgcn_global_load_lds( \
    (const __attribute__((address_space(1))) void*)(gp), \
    (__attribute__((address_space(3))) void*)(lp), 16, 0, 0)

__device__ __forceinline__ u16 f2bf(float f) {
  union { float f; unsigned u; } v; v.f = f;
  unsigned r = v.u + 0x7fffu + ((v.u >> 16) & 1u);
  return (u16)(r >> 16);
}

__device__ __forceinline__ u32 cvtpk(float lo, float hi) {
  u32 r;
  asm("v_cvt_pk_bf16_f32 %0, %1, %2" : "=v"(r) : "v"(lo), "v"(hi));
  return r;
}

// ---------------- W transpose + bf16 convert (+ fold 1/8 into WQ) ----------------
__global__ __launch_bounds__(256) void ktrans(const float* __restrict__ WQ,
                                              const float* __restrict__ WK,
                                              const float* __restrict__ WV,
                                              u16* __restrict__ Wt) {
  int z = blockIdx.z;
  const float* W = (z == 0) ? WQ : (z == 1) ? WK : WV;
  u16* o = Wt + (size_t)z * 1024 * 1024;
  float scale = (z == 0) ? 0.125f : 1.0f;
  __shared__ float tl[32][33];
  int tx = threadIdx.x & 31, ty = threadIdx.x >> 5;
  int ko = blockIdx.x * 32, no = blockIdx.y * 32;
#pragma unroll
  for (int i = 0; i < 32; i += 8)
    tl[ty + i][tx] = W[(size_t)(ko + ty + i) * 1024 + no + tx];
  __syncthreads();
#pragma unroll
  for (int i = 0; i < 32; i += 8)
    o[(size_t)(no + ty + i) * 1024 + ko + tx] = f2bf(tl[tx][ty + i] * scale);
}

// ---------------- projection GEMM: A[f32] @ Wt^T -> bf16 Q/K [b,h,s,d], V^T [b,h,d,s] ----
__global__ __launch_bounds__(256, 2) void kproj(
    const float* __restrict__ A0, const float* __restrict__ A1, const float* __restrict__ A2,
    const u16* __restrict__ Wt, u16* __restrict__ Qw, u16* __restrict__ Kw, u16* __restrict__ Vt) {
  int z = blockIdx.z;
  const float* A = (z == 0) ? A0 : (z == 1) ? A1 : A2;
  const u16* Wz = Wt + (size_t)z * 1024 * 1024;
  __shared__ __align__(16) u16 lds[16384];  // A tile [128][64] @0, B tile @8192, swizzled
  int t = threadIdx.x;
  int lane = t & 63, w = t >> 6;
  int wm = (w >> 1) * 64, wn = (w & 1) * 64;
  int m0 = blockIdx.y * 128, n0 = blockIdx.x * 128;
  f32x4 acc[4][4];
#pragma unroll
  for (int i = 0; i < 4; ++i)
#pragma unroll
    for (int j = 0; j < 4; ++j) acc[i][j] = (f32x4){0.f, 0.f, 0.f, 0.f};

  int srow = t >> 3, sk8 = (t & 7) << 3;  // staging: row, 8-elem k-chunk
  int lbw = (t >> 6) * 512;               // wave-uniform LDS elem base (1 KB/wave)

  for (int k0 = 0; k0 < 1024; k0 += 64) {
    __syncthreads();
    // B tile via global_load_lds (pre-swizzled source, linear LDS dest)
#pragma unroll
    for (int p = 0; p < 4; ++p) {
      int row = srow + p * 32;
      const u16* gp = Wz + (size_t)(n0 + row) * 1024 + k0 + (sk8 ^ ((row & 7) << 3));
      GLDS(gp, &lds[8192 + p * 2048 + lbw]);
    }
    // A tile reg-staged: f32 -> bf16 via cvt_pk, swizzled ds_write_b128
#pragma unroll
    for (int p = 0; p < 4; ++p) {
      int row = srow + p * 32;
      const float* ap = A + (size_t)(m0 + row) * 1024 + k0 + sk8;
      f32x4 v0 = *(const f32x4*)ap, v1 = *(const f32x4*)(ap + 4);
      union { u32 u[4]; u16x8 v; } pk;
      pk.u[0] = cvtpk(v0.x, v0.y); pk.u[1] = cvtpk(v0.z, v0.w);
      pk.u[2] = cvtpk(v1.x, v1.y); pk.u[3] = cvtpk(v1.z, v1.w);
      *(u16x8*)(&lds[row * 64 + (sk8 ^ ((row & 7) << 3))]) = pk.v;
    }
    __syncthreads();
#pragma unroll
    for (int kk = 0; kk < 64; kk += 32) {
      int ko8 = kk + ((lane >> 4) << 3);
      bf16x8 af[4], bfr[4];
#pragma unroll
      for (int mi = 0; mi < 4; ++mi) {
        int r = wm + mi * 16 + (lane & 15);
        af[mi] = *(const bf16x8*)(&lds[r * 64 + (ko8 ^ ((r & 7) << 3))]);
      }
#pragma unroll
      for (int ni = 0; ni < 4; ++ni) {
        int r = wn + ni * 16 + (lane & 15);
        bfr[ni] = *(const bf16x8*)(&lds[8192 + r * 64 + (ko8 ^ ((r & 7) << 3))]);
      }
#pragma unroll
      for (int mi = 0; mi < 4; ++mi)
#pragma unroll
        for (int ni = 0; ni < 4; ++ni)
          acc[mi][ni] = __builtin_amdgcn_mfma_f32_16x16x32_bf16(af[mi], bfr[ni], acc[mi][ni], 0, 0, 0);
    }
  }
  int bb = m0 >> 11;
  if (z < 2) {
    u16* o = (z == 0) ? Qw : Kw;
#pragma unroll
    for (int mi = 0; mi < 4; ++mi) {
      int m4 = m0 + wm + mi * 16 + ((lane >> 4) << 2);
      int s4 = m4 & 2047;
#pragma unroll
      for (int ni = 0; ni < 4; ++ni) {
        int n = n0 + wn + ni * 16 + (lane & 15);
        int hh = n >> 6, d = n & 63;
        u16* op = o + (((size_t)(bb * 16 + hh) * 2048 + s4) * 64 + d);
#pragma unroll
        for (int j = 0; j < 4; ++j) op[(size_t)j * 64] = f2bf(acc[mi][ni][j]);
      }
    }
  } else {
#pragma unroll
    for (int mi = 0; mi < 4; ++mi) {
      int m4 = m0 + wm + mi * 16 + ((lane >> 4) << 2);
      int s4 = m4 & 2047;
#pragma unroll
      for (int ni = 0; ni < 4; ++ni) {
        int n = n0 + wn + ni * 16 + (lane & 15);
        int hh = n >> 6, d = n & 63;
        u16x4 pv = {f2bf(acc[mi][ni][0]), f2bf(acc[mi][ni][1]),
                    f2bf(acc[mi][ni][2]), f2bf(acc[mi][ni][3])};
        *(u16x4*)(&Vt[((size_t)(bb * 16 + hh) * 64 + d) * 2048 + s4]) = pv;
      }
    }
  }
}

// ---------------- flash attention: 8 waves x 32 q-rows, swapped QK^T, in-register softmax ----
// S^T = mfma(A=K, B=Q): lane owns q-col = lane&31; rows kv = (reg&3)+8*(reg>>2)+4*(lane>>5).
// O^T = mfma(A=V^T, B=P^T): rescale factor lane-local. P^T built via cvt_pk + permlane32_swap.
__global__ __launch_bounds__(512, 4) void kattn(
    const u16* __restrict__ Qw, const u16* __restrict__ Kw, const u16* __restrict__ Vt,
    const int* __restrict__ Qlen, const int* __restrict__ Vlen, float* __restrict__ out) {
  int fid = blockIdx.x;
  int bh = (fid & 7) * 8 + (fid >> 6);  // XCD-chunked: 8 heads (4 MB K/V) per XCD L2
  int qx = (fid >> 3) & 7;
  int b = bh >> 4, h = bh & 15;
  int q0 = qx * 256;
  int t = threadIdx.x, lane = t & 63, w = t >> 6, hi = lane >> 5, ln = lane & 31;
  __shared__ __align__(16) u16 smem[16384];  // dbuf: [K 4096 | V 4096] x2, swizzled rows
  const int qlen = Qlen[b], vlen = Vlen[b];

  // Q B-frags straight from global: col q = ln, d = 16r + 8hi + j
  const u16* Qp = Qw + ((size_t)bh * 2048 + q0 + w * 32 + ln) * 64;
  bf16x8 qf[4];
#pragma unroll
  for (int r = 0; r < 4; ++r) qf[r] = *(const bf16x8*)(Qp + r * 16 + hi * 8);

  // staging coords (512 thr x 16B = 8KB/pass; K then V)
  int srow = t >> 3;
  int sks = (((t & 7) << 4) ^ ((srow & 7) << 4)) >> 1;  // pre-swizzled elem offset in row
  const u16* gK = Kw + ((size_t)bh * 2048 + srow) * 64 + sks;
  const u16* gV = Vt + ((size_t)bh * 64 + srow) * 2048 + sks;
  int lbw = (t >> 6) * 512;  // wave-uniform LDS elem base

  GLDS(gK, &smem[lbw]);            // tile 0 -> buf 0
  GLDS(gV, &smem[4096 + lbw]);

  float M = -1e30f, Lloc = 0.f;
  f32x16 o0, o1;
#pragma unroll
  for (int i = 0; i < 16; ++i) { o0[i] = 0.f; o1[i] = 0.f; }
  __syncthreads();

  for (int kt = 0; kt < 32; ++kt) {
    int qb = (kt & 1) * 8192;
    int nb = ((kt & 1) ^ 1) * 8192;
    if (kt < 31) {  // prefetch next tile into other buffer (drained by end-of-loop barrier)
      GLDS(gK + (size_t)(kt + 1) * 4096, &smem[nb + lbw]);
      GLDS(gV + (kt + 1) * 64, &smem[nb + 4096 + lbw]);
    }
    // S^T = K . Q^T
    f32x16 sa[2];
#pragma unroll
    for (int kb = 0; kb < 2; ++kb)
#pragma unroll
      for (int i = 0; i < 16; ++i) sa[kb][i] = 0.f;
#pragma unroll
    for (int kb = 0; kb < 2; ++kb) {
      int row = kb * 32 + ln;
      int rs7 = (row & 7) << 4;
#pragma unroll
      for (int r = 0; r < 4; ++r) {
        int byt = row * 128 + ((r * 32 + hi * 16) ^ rs7);
        bf16x8 kf = *(const bf16x8*)(&smem[qb + (byt >> 1)]);
        sa[kb] = __builtin_amdgcn_mfma_f32_32x32x16_bf16(kf, qf[r], sa[kb], 0, 0, 0);
      }
    }
    // V_len key mask (hits exactly one tile; block-uniform branch)
    if ((vlen >> 6) == kt) {
#pragma unroll
      for (int kb = 0; kb < 2; ++kb)
#pragma unroll
        for (int i = 0; i < 16; ++i) {
          int kv = (kt << 6) + kb * 32 + ((i & 3) + ((i >> 2) << 3)) + (hi << 2);
          if (kv == vlen) sa[kb][i] = -1e12f;
        }
    }
    // online softmax, lane-local row; pair (lane, lane^32) shares the row
    float tmax = sa[0][0];
#pragma unroll
    for (int i = 1; i < 16; ++i) tmax = fmaxf(tmax, sa[0][i]);
#pragma unroll
    for (int i = 0; i < 16; ++i) tmax = fmaxf(tmax, sa[1][i]);
    tmax = fmaxf(tmax, __shfl_xor(tmax, 32, 64));
    if (!__all(tmax - M <= 8.f)) {  // defer-max (T13)
      float Mn = fmaxf(M, tmax);
      float al = __expf(M - Mn);
      M = Mn;
      Lloc *= al;
#pragma unroll
      for (int i = 0; i < 16; ++i) { o0[i] *= al; o1[i] *= al; }
    }
    float rs = 0.f;
#pragma unroll
    for (int kb = 0; kb < 2; ++kb)
#pragma unroll
      for (int i = 0; i < 16; ++i) {
        float p = __expf(sa[kb][i] - M);
        sa[kb][i] = p;
        rs += p;
      }
    Lloc += rs;
    // P^T B-frags: cvt_pk + permlane32_swap (T12)
    bf16x8 pf[4];
#pragma unroll
    for (int kb = 0; kb < 2; ++kb)
#pragma unroll
      for (int f = 0; f < 2; ++f) {
        u32 a0 = cvtpk(sa[kb][8 * f + 0], sa[kb][8 * f + 1]);
        u32 b0 = cvtpk(sa[kb][8 * f + 4], sa[kb][8 * f + 5]);
        u32x2 r0 = __builtin_amdgcn_permlane32_swap(a0, b0, false, false);
        u32 a1 = cvtpk(sa[kb][8 * f + 2], sa[kb][8 * f + 3]);
        u32 b1 = cvtpk(sa[kb][8 * f + 6], sa[kb][8 * f + 7]);
        u32x2 r1 = __builtin_amdgcn_permlane32_swap(a1, b1, false, false);
        union { u32 u[4]; bf16x8 v; } uu;
        uu.u[0] = r0.x; uu.u[1] = r1.x; uu.u[2] = r0.y; uu.u[3] = r1.y;
        pf[kb * 2 + f] = uu.v;
      }
    // O^T += V^T . P^T
#pragma unroll
    for (int db = 0; db < 2; ++db) {
      int row = db * 32 + ln;
      int rs7 = (row & 7) << 4;
#pragma unroll
      for (int s4 = 0; s4 < 4; ++s4) {
        int byt = row * 128 + ((s4 * 32 + hi * 16) ^ rs7);
        bf16x8 vf = *(const bf16x8*)(&smem[qb + 4096 + (byt >> 1)]);
        if (db == 0) o0 = __builtin_amdgcn_mfma_f32_32x32x16_bf16(vf, pf[s4], o0, 0, 0, 0);
        else         o1 = __builtin_amdgcn_mfma_f32_32x32x16_bf16(vf, pf[s4], o1, 0, 0, 0);
      }
    }
    __syncthreads();  // drains prefetch vmcnt + guards buffer reuse
  }
  // epilogue: L across halves, /L, zero q==Q_len, f32 out [b, q, h*64+d]
  float Lt = Lloc + __shfl_xor(Lloc, 32, 64);
  int q = q0 + w * 32 + ln;
  float inv = (q == qlen) ? 0.f : 1.f / Lt;
  float* op = out + ((size_t)b * 2048 + q) * 1024 + h * 64;
#pragma unroll
  for (int g = 0; g < 4; ++g) {
    f32x4 v0 = {o0[4 * g + 0] * inv, o0[4 * g + 1] * inv, o0[4 * g + 2] * inv, o0[4 * g + 3] * inv};
    *(f32x4*)(op + g * 8 + hi * 4) = v0;
    f32x4 v1 = {o1[4 * g + 0] * inv, o1[4 * g + 1] * inv, o1[4 * g + 2] * inv, o1[4 * g + 3] * inv};
    *(f32x4*)(op + 32 + g * 8 + hi * 4) = v1;
  }
}

extern "C" void kernel_launch(void* const* d_in, const int* in_sizes, int n_in,
                              void* d_out, int out_size, void* d_ws, size_t ws_size,
                              hipStream_t stream) {
  (void)in_sizes; (void)n_in; (void)out_size; (void)ws_size;
  const float* Qs = (const float*)d_in[0];
  const float* Ks = (const float*)d_in[1];
  const float* Vs = (const float*)d_in[2];
  const int* Ql = (const int*)d_in[3];
  const int* Vl = (const int*)d_in[4];
  const float* WQ = (const float*)d_in[5];
  const float* WK = (const float*)d_in[6];
  const float* WV = (const float*)d_in[7];
  float* out = (float*)d_out;

  u16* Wt = (u16*)d_ws;                    // 3 * 1M bf16 = 6 MB
  u16* Qw = Wt + (size_t)3 * 1024 * 1024;  // each 16 MB
  u16* Kw = Qw + (size_t)8 * 1024 * 1024;
  u16* Vtw = Kw + (size_t)8 * 1024 * 1024;

  ktrans<<<dim3(32, 32, 3), 256, 0, stream>>>(WQ, WK, WV, Wt);
  kproj<<<dim3(8, 64, 3), 256, 0, stream>>>(Qs, Ks, Vs, Wt, Qw, Kw, Vtw);
  kattn<<<512, 512, 0, stream>>>(Qw, Kw, Vtw, Ql, Vl, out);
}